// Round 13
// baseline (3499.244 us; speedup 1.0000x reference)
//
#include <hip/hip_runtime.h>

#define SEQ  512
#define IDIM 256
#define H    1024
#define NC   128
#define B    256
#define NBLK 256   // 16 groups x 16 WGs (16 rows x 64 cols each)

typedef __attribute__((ext_vector_type(8))) short bh8;
typedef __attribute__((ext_vector_type(4))) float f4;

__device__ __forceinline__ float sigf(float x) { return 1.0f / (1.0f + __expf(-x)); }

__device__ __forceinline__ unsigned short bf16r(float v) {
    unsigned u = __builtin_bit_cast(unsigned, v);
    u += 0x7fffu + ((u >> 16) & 1u);
    return (unsigned short)(u >> 16);
}

// ---------------- token tables: FF/II/OO = emb@W*x.T + b*, G = sigmoid(emb@Wcx.T + bc) ----
__global__ __launch_bounds__(256) void tables_kernel(
    const float* __restrict__ emb,
    const float* __restrict__ Wcx, const float* __restrict__ bc,
    const float* __restrict__ Wix, const float* __restrict__ bi,
    const float* __restrict__ Wfx, const float* __restrict__ bf,
    const float* __restrict__ Wox, const float* __restrict__ bo,
    float* __restrict__ FF, float* __restrict__ II,
    float* __restrict__ OO, float* __restrict__ G)
{
    const int k = blockIdx.x;
    const int h = blockIdx.y * 256 + threadIdx.x;
    __shared__ float e[IDIM];
    e[threadIdx.x] = emb[k * IDIM + threadIdx.x];
    __syncthreads();
    const float4* e4  = (const float4*)e;
    const float4* wf4 = (const float4*)(Wfx + (size_t)h * IDIM);
    const float4* wi4 = (const float4*)(Wix + (size_t)h * IDIM);
    const float4* wo4 = (const float4*)(Wox + (size_t)h * IDIM);
    const float4* wc4 = (const float4*)(Wcx + (size_t)h * IDIM);
    float aF = 0.f, aI = 0.f, aO = 0.f, aC = 0.f;
#pragma unroll 4
    for (int i = 0; i < IDIM / 4; i++) {
        float4 ev = e4[i];
        float4 a = wf4[i]; aF += ev.x * a.x + ev.y * a.y + ev.z * a.z + ev.w * a.w;
        float4 b = wi4[i]; aI += ev.x * b.x + ev.y * b.y + ev.z * b.z + ev.w * b.w;
        float4 c = wo4[i]; aO += ev.x * c.x + ev.y * c.y + ev.z * c.z + ev.w * c.w;
        float4 d = wc4[i]; aC += ev.x * d.x + ev.y * d.y + ev.z * d.z + ev.w * d.w;
    }
    const int o = k * H + h;
    FF[o] = aF + bf[h];
    II[o] = aI + bi[h];
    OO[o] = aO + bo[h];
    G[o]  = sigf(aC + bc[h]);
}

// ---------------- weight fp32 -> bf16 swizzled for MFMA B-fragments -----------------------
__global__ __launch_bounds__(256) void swz_kernel(const float* __restrict__ W,
                                                  unsigned short* __restrict__ D)
{
    int g = blockIdx.x * 256 + threadIdx.x;     // 0..131071
    int h  = g >> 7;
    int kc = (g & 127) << 3;
    const float4* s = (const float4*)(W + (size_t)h * H + kc);
    float4 a = s[0], b = s[1];
    unsigned short tmp[8] = { bf16r(a.x), bf16r(a.y), bf16r(a.z), bf16r(a.w),
                              bf16r(b.x), bf16r(b.y), bf16r(b.z), bf16r(b.w) };
    int nb = h >> 4, kb = kc >> 5, quad = (kc >> 3) & 3;
    int lane = (h & 15) + (quad << 4);
    bh8 v;
#pragma unroll
    for (int j = 0; j < 8; j++) v[j] = (short)tmp[j];
    *(bh8*)(D + (size_t)((nb * 32 + kb) * 512 + lane * 8)) = v;
}

// ------- persistent recurrence: WAVE-AUTONOMOUS, direct A-frag loads, no LDS/no sync ------
// A-frag for lane (l15=row, quad=k-offset) is 16 contiguous bytes in the exchange buffer,
// so MFMA A-operands load STRAIGHT from LLC: batches of 8, double-buffered (16 in flight),
// waits via register-TIED s_waitcnt (ties make the MFMA data-dependent on the wait — the
// r10 reorder bug is impossible). Per-wave flags as r12: flag s+1 posts after this wave's
// step-s A-loads are consumed AND its c_{s+1} stores drained => poll(all>=s) protects the
// ping-pong buffer on both sides. Waves never rendezvous: max slip 1 step.
__global__ __launch_bounds__(256, 1) void persist_kernel(
    const unsigned short* __restrict__ Wf, const unsigned short* __restrict__ Wi,
    const unsigned short* __restrict__ Wo,
    const float* __restrict__ FF, const float* __restrict__ II,
    const float* __restrict__ OO, const float* __restrict__ G,
    const int* __restrict__ x,
    unsigned short* c16a, unsigned short* c16b,
    float* __restrict__ hb, int* flags)
{
    const int blk = blockIdx.x;         // 0..255
    const int rt = blk >> 4;            // group 0..15 (16 batch rows) — groups independent
    const int nt = blk & 15;            // 64-col tile 0..15 within group
    const int tid  = threadIdx.x;
    const int wave = tid >> 6;          // wave owns 16 cols, all 16 group rows
    const int lane = tid & 63;
    const int l15 = lane & 15, quad = lane >> 4;

    const int row0 = rt * 16;
    const int hcol = nt * 64 + wave * 16 + l15;
    const int nb = nt * 4 + wave;              // 16-col weight block 0..63

    const unsigned short* wfp = Wf + (size_t)nb * 32 * 512 + (size_t)lane * 8;
    const unsigned short* wip = Wi + (size_t)nb * 32 * 512 + (size_t)lane * 8;
    const unsigned short* wop = Wo + (size_t)nb * 32 * 512 + (size_t)lane * 8;

    // loop-invariant F/I weight fragments in VGPRs (1 KB/lane)
    bh8 wf_r[32], wi_r[32];
#pragma unroll
    for (int kt = 0; kt < 32; kt++) {
        wf_r[kt] = *(const bh8*)(wfp + (size_t)kt * 512);
        wi_r[kt] = *(const bh8*)(wip + (size_t)kt * 512);
    }

    float cn_keep[4] = {0.f, 0.f, 0.f, 0.f};   // fp32 cell state in registers
    int* const myflag = flags + rt * 64 + nt * 4 + wave;   // per-wave flag
    const int* const pf = flags + rt * 64 + lane;          // 64 group flags, coalesced

    // this lane's A-frag row base in the exchange buffers
    const size_t aoff = (size_t)(row0 + l15) * H + quad * 8;

    for (int s = 0; s < SEQ; s++) {
        const unsigned short* cur16 = (s & 1) ? c16b : c16a;
        unsigned short*       nxt16 = (s & 1) ? c16a : c16b;

        // token/table prefetch — in flight while we poll
        float ffv[4], iiv[4], ggv[4];
#pragma unroll
        for (int r = 0; r < 4; r++) {
            int b = row0 + quad * 4 + r;
            int tok = x[b * SEQ + s];
            ffv[r] = FF[tok * H + hcol];
            iiv[r] = II[tok * H + hcol];
            ggv[r] = G[tok * H + hcol];
        }

        f4 accF = {0.f, 0.f, 0.f, 0.f}, accI = {0.f, 0.f, 0.f, 0.f};
        if (s > 0) {
            // per-wave poll: all 64 group flags (one coalesced lane-load each)
            {
                int guard = 0;
                for (;;) {
                    int fv;
                    asm volatile("global_load_dword %0, %1, off sc0 sc1\n\ts_waitcnt vmcnt(0)"
                                 : "=v"(fv) : "v"(pf) : "memory");
                    if (__all(fv >= s)) break;
                    if (++guard > (1 << 20)) break;   // hang bailout (debug)
                }
            }
            // direct A-frag stream: 4 batches x 8 frags, double-buffered (16 in flight)
            const unsigned short* arow = cur16 + aoff;
            bh8 a0[8], a1[8];
#pragma unroll
            for (int j = 0; j < 8; j++)
                asm volatile("global_load_dwordx4 %0, %1, off sc0 sc1"
                             : "=v"(a0[j]) : "v"(arow + j * 32));
#pragma unroll
            for (int j = 0; j < 8; j++)
                asm volatile("global_load_dwordx4 %0, %1, off sc0 sc1"
                             : "=v"(a1[j]) : "v"(arow + (8 + j) * 32));
#pragma unroll
            for (int b = 0; b < 4; b++) {
                bh8* cur = (b & 1) ? a1 : a0;
                if (b < 3)
                    asm volatile("s_waitcnt vmcnt(8)"
                        : "+v"(cur[0]), "+v"(cur[1]), "+v"(cur[2]), "+v"(cur[3]),
                          "+v"(cur[4]), "+v"(cur[5]), "+v"(cur[6]), "+v"(cur[7]) :: "memory");
                else
                    asm volatile("s_waitcnt vmcnt(0)"
                        : "+v"(cur[0]), "+v"(cur[1]), "+v"(cur[2]), "+v"(cur[3]),
                          "+v"(cur[4]), "+v"(cur[5]), "+v"(cur[6]), "+v"(cur[7]) :: "memory");
#pragma unroll
                for (int j = 0; j < 8; j++) {
                    int kt = b * 8 + j;
                    accF = __builtin_amdgcn_mfma_f32_16x16x32_bf16(cur[j], wf_r[kt], accF, 0, 0, 0);
                    accI = __builtin_amdgcn_mfma_f32_16x16x32_bf16(cur[j], wi_r[kt], accI, 0, 0, 0);
                }
                if (b < 2) {
#pragma unroll
                    for (int j = 0; j < 8; j++)
                        asm volatile("global_load_dwordx4 %0, %1, off sc0 sc1"
                                     : "=v"(cur[j]) : "v"(arow + ((b + 2) * 8 + j) * 32));
                }
            }
        }

        // epilogue: C/D col=lane&15, row=quad*4+reg; pack 2 cols/dword, store to LLC
#pragma unroll
        for (int r = 0; r < 4; r++) {
            float f = sigf(ffv[r] + accF[r]);
            float i = sigf(iiv[r] + accI[r]);
            float cn = ggv[r] * i + cn_keep[r] * f;
            cn_keep[r] = cn;
            int b = row0 + quad * 4 + r;
            unsigned us = bf16r(cn);
            unsigned ot = (unsigned)__shfl_xor((int)us, 1);
            if (s < SEQ - 1 && (lane & 1) == 0)
                __hip_atomic_store((unsigned*)(nxt16 + (size_t)b * H + hcol), us | (ot << 16),
                                   __ATOMIC_RELAXED, __HIP_MEMORY_SCOPE_AGENT);
        }

        if (s < SEQ - 1) {
            // per-wave arrive: drain MY stores to LLC, post MY flag
            asm volatile("s_waitcnt vmcnt(0)" ::: "memory");
            if (lane == 0) {
                int v = s + 1;
                asm volatile("global_store_dword %0, %1, off sc0 sc1"
                             :: "v"(myflag), "v"(v) : "memory");
            }
        }
    }

    // o-gate: reload c_511 A-frags from the exchange buffer (c16b), same pipelined pattern
    {
        const unsigned short* arow = c16b + aoff;
        f4 accO = {0.f, 0.f, 0.f, 0.f};
        bh8 a0[8], a1[8];
#pragma unroll
        for (int j = 0; j < 8; j++)
            asm volatile("global_load_dwordx4 %0, %1, off sc0 sc1"
                         : "=v"(a0[j]) : "v"(arow + j * 32));
#pragma unroll
        for (int j = 0; j < 8; j++)
            asm volatile("global_load_dwordx4 %0, %1, off sc0 sc1"
                         : "=v"(a1[j]) : "v"(arow + (8 + j) * 32));
#pragma unroll
        for (int b = 0; b < 4; b++) {
            bh8* cur = (b & 1) ? a1 : a0;
            if (b < 3)
                asm volatile("s_waitcnt vmcnt(8)"
                    : "+v"(cur[0]), "+v"(cur[1]), "+v"(cur[2]), "+v"(cur[3]),
                      "+v"(cur[4]), "+v"(cur[5]), "+v"(cur[6]), "+v"(cur[7]) :: "memory");
            else
                asm volatile("s_waitcnt vmcnt(0)"
                    : "+v"(cur[0]), "+v"(cur[1]), "+v"(cur[2]), "+v"(cur[3]),
                      "+v"(cur[4]), "+v"(cur[5]), "+v"(cur[6]), "+v"(cur[7]) :: "memory");
#pragma unroll
            for (int j = 0; j < 8; j++) {
                int kt = b * 8 + j;
                bh8 bo = *(const bh8*)(wop + (size_t)kt * 512);
                accO = __builtin_amdgcn_mfma_f32_16x16x32_bf16(cur[j], bo, accO, 0, 0, 0);
            }
            if (b < 2) {
#pragma unroll
                for (int j = 0; j < 8; j++)
                    asm volatile("global_load_dwordx4 %0, %1, off sc0 sc1"
                                 : "=v"(cur[j]) : "v"(arow + ((b + 2) * 8 + j) * 32));
            }
        }
#pragma unroll
        for (int r = 0; r < 4; r++) {
            int b = row0 + quad * 4 + r;
            int tok = x[b * SEQ + (SEQ - 1)];
            float o = sigf(OO[tok * H + hcol] + accO[r]);
            hb[(size_t)b * H + hcol] = tanhf(cn_keep[r]) * o;
        }
    }
}

// ---------------- p = h @ Wph.T + bp ; out = log_softmax(p) -------------------------------
__global__ __launch_bounds__(128) void out_kernel(
    const float* __restrict__ hbuf, const float* __restrict__ Wph,
    const float* __restrict__ bp, float* __restrict__ out)
{
    const int b = blockIdx.x;
    const int j = threadIdx.x;
    __shared__ float hs[H];
    for (int t = j; t < H; t += 128) hs[t] = hbuf[(size_t)b * H + t];
    __syncthreads();
    const float4* w4 = (const float4*)(Wph + (size_t)j * H);
    const float4* h4 = (const float4*)hs;
    float acc = bp[j];
#pragma unroll 4
    for (int k = 0; k < H / 4; k++) {
        float4 a = w4[k], v = h4[k];
        acc += a.x * v.x + a.y * v.y + a.z * v.z + a.w * v.w;
    }
    __shared__ float red[128];
    red[j] = acc; __syncthreads();
    for (int off = 64; off > 0; off >>= 1) { if (j < off) red[j] = fmaxf(red[j], red[j + off]); __syncthreads(); }
    float m = red[0]; __syncthreads();
    red[j] = __expf(acc - m); __syncthreads();
    for (int off = 64; off > 0; off >>= 1) { if (j < off) red[j] += red[j + off]; __syncthreads(); }
    float lse = m + __logf(red[0]);
    out[(size_t)b * NC + j] = acc - lse;
}

extern "C" void kernel_launch(void* const* d_in, const int* in_sizes, int n_in,
                              void* d_out, int out_size, void* d_ws, size_t ws_size,
                              hipStream_t stream)
{
    const int*   x   = (const int*)d_in[0];
    const float* emb = (const float*)d_in[1];
    const float* Wcx = (const float*)d_in[2];
    const float* bc  = (const float*)d_in[3];
    const float* Wix = (const float*)d_in[4];
    const float* Wih = (const float*)d_in[5];
    const float* bi  = (const float*)d_in[6];
    const float* Wfx = (const float*)d_in[7];
    const float* Wfh = (const float*)d_in[8];
    const float* bf  = (const float*)d_in[9];
    const float* Wox = (const float*)d_in[10];
    const float* Woh = (const float*)d_in[11];
    const float* bo  = (const float*)d_in[12];
    const float* Wph = (const float*)d_in[13];
    const float* bp  = (const float*)d_in[14];
    float* out = (float*)d_out;

    char* wsb = (char*)d_ws;
    float* FF = (float*)(wsb + 0);                         // 512 KB
    float* II = (float*)(wsb + (512 << 10));
    float* OO = (float*)(wsb + (1024 << 10));
    float* G  = (float*)(wsb + (1536 << 10));
    float* hb = (float*)(wsb + (2048 << 10));              // 1 MB
    int*   flags = (int*)(wsb + (3072 << 10));             // 4 KB (16 groups x 64 wave-flags)
    unsigned short* Wf_sw = (unsigned short*)(wsb + (4096 << 10));   // 2 MB each
    unsigned short* Wi_sw = (unsigned short*)(wsb + (6144 << 10));
    unsigned short* Wo_sw = (unsigned short*)(wsb + (8192 << 10));
    unsigned short* c16a  = (unsigned short*)(wsb + (10240 << 10));  // 512 KB each
    unsigned short* c16b  = (unsigned short*)(wsb + (10752 << 10));

    hipMemsetAsync(flags, 0, 4096, stream);   // barrier flags = 0

    tables_kernel<<<dim3(NC, 4), 256, 0, stream>>>(emb, Wcx, bc, Wix, bi, Wfx, bf, Wox, bo,
                                                   FF, II, OO, G);
    swz_kernel<<<512, 256, 0, stream>>>(Wfh, Wf_sw);
    swz_kernel<<<512, 256, 0, stream>>>(Wih, Wi_sw);
    swz_kernel<<<512, 256, 0, stream>>>(Woh, Wo_sw);

    persist_kernel<<<NBLK, 256, 0, stream>>>(Wf_sw, Wi_sw, Wo_sw, FF, II, OO, G, x,
                                             c16a, c16b, hb, flags);

    out_kernel<<<B, 128, 0, stream>>>(hb, Wph, bp, out);
}

// Round 14
// 2306.723 us; speedup vs baseline: 1.5170x; 1.5170x over previous
//
#include <hip/hip_runtime.h>

#define SEQ  512
#define IDIM 256
#define H    1024
#define NC   128
#define B    256
#define NBLK 256   // 16 groups x 16 WGs (16 rows x 64 cols each)

typedef __attribute__((ext_vector_type(8))) short bh8;
typedef __attribute__((ext_vector_type(4))) float f4;
typedef __attribute__((ext_vector_type(4))) int i4;

__device__ __forceinline__ float sigf(float x) { return 1.0f / (1.0f + __expf(-x)); }

__device__ __forceinline__ unsigned short bf16r(float v) {
    unsigned u = __builtin_bit_cast(unsigned, v);
    u += 0x7fffu + ((u >> 16) & 1u);
    return (unsigned short)(u >> 16);
}

// ---------------- token tables: FF/II/OO = emb@W*x.T + b*, G = sigmoid(emb@Wcx.T + bc) ----
__global__ __launch_bounds__(256) void tables_kernel(
    const float* __restrict__ emb,
    const float* __restrict__ Wcx, const float* __restrict__ bc,
    const float* __restrict__ Wix, const float* __restrict__ bi,
    const float* __restrict__ Wfx, const float* __restrict__ bf,
    const float* __restrict__ Wox, const float* __restrict__ bo,
    float* __restrict__ FF, float* __restrict__ II,
    float* __restrict__ OO, float* __restrict__ G)
{
    const int k = blockIdx.x;
    const int h = blockIdx.y * 256 + threadIdx.x;
    __shared__ float e[IDIM];
    e[threadIdx.x] = emb[k * IDIM + threadIdx.x];
    __syncthreads();
    const float4* e4  = (const float4*)e;
    const float4* wf4 = (const float4*)(Wfx + (size_t)h * IDIM);
    const float4* wi4 = (const float4*)(Wix + (size_t)h * IDIM);
    const float4* wo4 = (const float4*)(Wox + (size_t)h * IDIM);
    const float4* wc4 = (const float4*)(Wcx + (size_t)h * IDIM);
    float aF = 0.f, aI = 0.f, aO = 0.f, aC = 0.f;
#pragma unroll 4
    for (int i = 0; i < IDIM / 4; i++) {
        float4 ev = e4[i];
        float4 a = wf4[i]; aF += ev.x * a.x + ev.y * a.y + ev.z * a.z + ev.w * a.w;
        float4 b = wi4[i]; aI += ev.x * b.x + ev.y * b.y + ev.z * b.z + ev.w * b.w;
        float4 c = wo4[i]; aO += ev.x * c.x + ev.y * c.y + ev.z * c.z + ev.w * c.w;
        float4 d = wc4[i]; aC += ev.x * d.x + ev.y * d.y + ev.z * d.z + ev.w * d.w;
    }
    const int o = k * H + h;
    FF[o] = aF + bf[h];
    II[o] = aI + bi[h];
    OO[o] = aO + bo[h];
    G[o]  = sigf(aC + bc[h]);
}

// ---------------- weight fp32 -> bf16 swizzled for MFMA B-fragments -----------------------
__global__ __launch_bounds__(256) void swz_kernel(const float* __restrict__ W,
                                                  unsigned short* __restrict__ D)
{
    int g = blockIdx.x * 256 + threadIdx.x;     // 0..131071
    int h  = g >> 7;
    int kc = (g & 127) << 3;
    const float4* s = (const float4*)(W + (size_t)h * H + kc);
    float4 a = s[0], b = s[1];
    unsigned short tmp[8] = { bf16r(a.x), bf16r(a.y), bf16r(a.z), bf16r(a.w),
                              bf16r(b.x), bf16r(b.y), bf16r(b.z), bf16r(b.w) };
    int nb = h >> 4, kb = kc >> 5, quad = (kc >> 3) & 3;
    int lane = (h & 15) + (quad << 4);
    bh8 v;
#pragma unroll
    for (int j = 0; j < 8; j++) v[j] = (short)tmp[j];
    *(bh8*)(D + (size_t)((nb * 32 + kb) * 512 + lane * 8)) = v;
}

// ------- persistent recurrence: r12 protocol + LLC-ALLOCATING atomic exchange stores ------
// r12 counters showed FETCH=2MB/step: sc1 plain stores are write-through NO-ALLOCATE, so
// staging reads partially bounce to HBM (~1000cy) on the critical path. Fix: exchange and
// flag stores become non-returning global_atomic_swap (executed AT the LLC -> line stays
// LLC-resident) so consumer sc0 sc1 loads are LLC hits. Protocol unchanged from r12:
// per-wave flags, flag s+1 posts after own drain; poll(all>=s) protects ping-pong both ways.
__global__ __launch_bounds__(256, 1) void persist_kernel(
    const unsigned short* __restrict__ Wf, const unsigned short* __restrict__ Wi,
    const unsigned short* __restrict__ Wo,
    const float* __restrict__ FF, const float* __restrict__ II,
    const float* __restrict__ OO, const float* __restrict__ G,
    const int* __restrict__ x,
    unsigned short* c16a, unsigned short* c16b,
    float* __restrict__ hb, int* flags)
{
    const int blk = blockIdx.x;         // 0..255
    const int rt = blk >> 4;            // group 0..15 (16 batch rows) — groups independent
    const int nt = blk & 15;            // 64-col tile 0..15 within group
    const int tid  = threadIdx.x;
    const int wave = tid >> 6;          // wave owns 16 cols, all 16 group rows
    const int lane = tid & 63;
    const int l15 = lane & 15, quad = lane >> 4;

    __shared__ unsigned short cs[16 * 1024];   // 32 KB, XOR-swizzled 16B granules

    const int row0 = rt * 16;
    const int abase = l15 * 1024;              // A-frag row (m = l15)
    const int asw = l15 & 7;
    const int hcol = nt * 64 + wave * 16 + l15;
    const int nb = nt * 4 + wave;              // 16-col weight block 0..63

    const unsigned short* wfp = Wf + (size_t)nb * 32 * 512 + (size_t)lane * 8;
    const unsigned short* wip = Wi + (size_t)nb * 32 * 512 + (size_t)lane * 8;
    const unsigned short* wop = Wo + (size_t)nb * 32 * 512 + (size_t)lane * 8;

    // loop-invariant F/I weight fragments in VGPRs (1 KB/lane)
    bh8 wf_r[32], wi_r[32];
#pragma unroll
    for (int kt = 0; kt < 32; kt++) {
        wf_r[kt] = *(const bh8*)(wfp + (size_t)kt * 512);
        wi_r[kt] = *(const bh8*)(wip + (size_t)kt * 512);
    }

    float cn_keep[4] = {0.f, 0.f, 0.f, 0.f};   // fp32 cell state in registers
    int* const myflag = flags + rt * 64 + nt * 4 + wave;   // per-wave flag
    const int* const pf = flags + rt * 64 + lane;          // 64 group flags, coalesced

    for (int s = 0; s < SEQ; s++) {
        const unsigned short* cur16 = (s & 1) ? c16b : c16a;
        unsigned short*       nxt16 = (s & 1) ? c16a : c16b;

        // token/table prefetch — in flight while we poll
        float ffv[4], iiv[4], ggv[4];
#pragma unroll
        for (int r = 0; r < 4; r++) {
            int b = row0 + quad * 4 + r;
            int tok = x[b * SEQ + s];
            ffv[r] = FF[tok * H + hcol];
            iiv[r] = II[tok * H + hcol];
            ggv[r] = G[tok * H + hcol];
        }

        f4 accF = {0.f, 0.f, 0.f, 0.f}, accI = {0.f, 0.f, 0.f, 0.f};
        if (s > 0) {
            // per-wave poll: every wave checks all 64 group flags itself
            {
                int guard = 0;
                for (;;) {
                    int fv;
                    asm volatile("global_load_dword %0, %1, off sc0 sc1\n\ts_waitcnt vmcnt(0)"
                                 : "=v"(fv) : "v"(pf) : "memory");
                    if (__all(fv >= s)) break;
                    if (++guard > (1 << 20)) break;   // hang bailout (debug)
                }
            }
            // stage 16 rows x 2 KB bf16 of c from LLC (now LLC-resident): 8 pipelined
            // loads/lane, ONE waitcnt (volatile+memory-clobber fences the LDS writes)
            i4 tmp[8];
#pragma unroll
            for (int i = 0; i < 8; i++) {
                int chunk = i * 256 + tid;           // 0..2047
                int row = chunk >> 7, g = chunk & 127;
                const i4* p = (const i4*)(cur16 + (size_t)(row0 + row) * H + g * 8);
                asm volatile("global_load_dwordx4 %0, %1, off sc0 sc1"
                             : "=v"(tmp[i]) : "v"(p));
            }
            asm volatile("s_waitcnt vmcnt(0)" ::: "memory");
#pragma unroll
            for (int i = 0; i < 8; i++) {
                int chunk = i * 256 + tid;
                int row = chunk >> 7, g = chunk & 127;
                *(i4*)(cs + row * 1024 + ((g ^ (row & 7)) << 3)) = tmp[i];
            }
            __syncthreads();   // the ONE per-step WG sync: LDS write -> MFMA read
#pragma unroll
            for (int kt = 0; kt < 32; kt++) {
                bh8 a = *(const bh8*)(cs + abase + (((kt * 4 + quad) ^ asw) << 3));
                accF = __builtin_amdgcn_mfma_f32_16x16x32_bf16(a, wf_r[kt], accF, 0, 0, 0);
                accI = __builtin_amdgcn_mfma_f32_16x16x32_bf16(a, wi_r[kt], accI, 0, 0, 0);
            }
        }

        // epilogue: C/D col=lane&15, row=quad*4+reg; pack 2 cols/dword.
        // Store via NON-RETURNING atomic swap (sc1, no sc0) -> executes at LLC, line
        // stays LLC-resident for the consumers' staging loads.
#pragma unroll
        for (int r = 0; r < 4; r++) {
            float f = sigf(ffv[r] + accF[r]);
            float i = sigf(iiv[r] + accI[r]);
            float cn = ggv[r] * i + cn_keep[r] * f;
            cn_keep[r] = cn;
            int b = row0 + quad * 4 + r;
            unsigned us = bf16r(cn);
            unsigned ot = (unsigned)__shfl_xor((int)us, 1);
            if (s < SEQ - 1 && (lane & 1) == 0) {
                unsigned dw = us | (ot << 16);
                unsigned* p = (unsigned*)(nxt16 + (size_t)b * H + hcol);
                asm volatile("global_atomic_swap %0, %1, off sc1"
                             :: "v"(p), "v"(dw) : "memory");
            }
        }

        if (s < SEQ - 1) {
            // per-wave arrive: drain MY atomics (completed at LLC), post MY flag (atomic)
            asm volatile("s_waitcnt vmcnt(0)" ::: "memory");
            if (lane == 0) {
                int v = s + 1;
                asm volatile("global_atomic_swap %0, %1, off sc1"
                             :: "v"(myflag), "v"(v) : "memory");
            }
        }
    }

    // o-gate: c_511 still staged in LDS; Wo streamed from L2 (used once)
    f4 accO = {0.f, 0.f, 0.f, 0.f};
#pragma unroll 4
    for (int kt = 0; kt < 32; kt++) {
        bh8 a  = *(const bh8*)(cs + abase + (((kt * 4 + quad) ^ asw) << 3));
        bh8 bo = *(const bh8*)(wop + (size_t)kt * 512);
        accO = __builtin_amdgcn_mfma_f32_16x16x32_bf16(a, bo, accO, 0, 0, 0);
    }
#pragma unroll
    for (int r = 0; r < 4; r++) {
        int b = row0 + quad * 4 + r;
        int tok = x[b * SEQ + (SEQ - 1)];
        float o = sigf(OO[tok * H + hcol] + accO[r]);
        hb[(size_t)b * H + hcol] = tanhf(cn_keep[r]) * o;
    }
}

// ---------------- p = h @ Wph.T + bp ; out = log_softmax(p) -------------------------------
__global__ __launch_bounds__(128) void out_kernel(
    const float* __restrict__ hbuf, const float* __restrict__ Wph,
    const float* __restrict__ bp, float* __restrict__ out)
{
    const int b = blockIdx.x;
    const int j = threadIdx.x;
    __shared__ float hs[H];
    for (int t = j; t < H; t += 128) hs[t] = hbuf[(size_t)b * H + t];
    __syncthreads();
    const float4* w4 = (const float4*)(Wph + (size_t)j * H);
    const float4* h4 = (const float4*)hs;
    float acc = bp[j];
#pragma unroll 4
    for (int k = 0; k < H / 4; k++) {
        float4 a = w4[k], v = h4[k];
        acc += a.x * v.x + a.y * v.y + a.z * v.z + a.w * v.w;
    }
    __shared__ float red[128];
    red[j] = acc; __syncthreads();
    for (int off = 64; off > 0; off >>= 1) { if (j < off) red[j] = fmaxf(red[j], red[j + off]); __syncthreads(); }
    float m = red[0]; __syncthreads();
    red[j] = __expf(acc - m); __syncthreads();
    for (int off = 64; off > 0; off >>= 1) { if (j < off) red[j] += red[j + off]; __syncthreads(); }
    float lse = m + __logf(red[0]);
    out[(size_t)b * NC + j] = acc - lse;
}

extern "C" void kernel_launch(void* const* d_in, const int* in_sizes, int n_in,
                              void* d_out, int out_size, void* d_ws, size_t ws_size,
                              hipStream_t stream)
{
    const int*   x   = (const int*)d_in[0];
    const float* emb = (const float*)d_in[1];
    const float* Wcx = (const float*)d_in[2];
    const float* bc  = (const float*)d_in[3];
    const float* Wix = (const float*)d_in[4];
    const float* Wih = (const float*)d_in[5];
    const float* bi  = (const float*)d_in[6];
    const float* Wfx = (const float*)d_in[7];
    const float* Wfh = (const float*)d_in[8];
    const float* bf  = (const float*)d_in[9];
    const float* Wox = (const float*)d_in[10];
    const float* Woh = (const float*)d_in[11];
    const float* bo  = (const float*)d_in[12];
    const float* Wph = (const float*)d_in[13];
    const float* bp  = (const float*)d_in[14];
    float* out = (float*)d_out;

    char* wsb = (char*)d_ws;
    float* FF = (float*)(wsb + 0);                         // 512 KB
    float* II = (float*)(wsb + (512 << 10));
    float* OO = (float*)(wsb + (1024 << 10));
    float* G  = (float*)(wsb + (1536 << 10));
    float* hb = (float*)(wsb + (2048 << 10));              // 1 MB
    int*   flags = (int*)(wsb + (3072 << 10));             // 4 KB (16 groups x 64 wave-flags)
    unsigned short* Wf_sw = (unsigned short*)(wsb + (4096 << 10));   // 2 MB each
    unsigned short* Wi_sw = (unsigned short*)(wsb + (6144 << 10));
    unsigned short* Wo_sw = (unsigned short*)(wsb + (8192 << 10));
    unsigned short* c16a  = (unsigned short*)(wsb + (10240 << 10));  // 512 KB each
    unsigned short* c16b  = (unsigned short*)(wsb + (10752 << 10));

    hipMemsetAsync(flags, 0, 4096, stream);   // barrier flags = 0

    tables_kernel<<<dim3(NC, 4), 256, 0, stream>>>(emb, Wcx, bc, Wix, bi, Wfx, bf, Wox, bo,
                                                   FF, II, OO, G);
    swz_kernel<<<512, 256, 0, stream>>>(Wfh, Wf_sw);
    swz_kernel<<<512, 256, 0, stream>>>(Wih, Wi_sw);
    swz_kernel<<<512, 256, 0, stream>>>(Woh, Wo_sw);

    persist_kernel<<<NBLK, 256, 0, stream>>>(Wf_sw, Wi_sw, Wo_sw, FF, II, OO, G, x,
                                             c16a, c16b, hb, flags);

    out_kernel<<<B, 128, 0, stream>>>(hb, Wph, bp, out);
}